// Round 6
// baseline (350.115 us; speedup 1.0000x reference)
//
#include <hip/hip_runtime.h>

#define NN 50000
#define NE 800000
#define NT (NE / 32)

// workspace layout (CSR + wave-reduced partials)
#define CNT_OFF   0u         // 50000 u32
#define CNT2_OFF  200704u    // 50000 u32
#define BASE_OFF  401408u    // 50001 u32
#define PART_OFF  601856u    // 196 u32 scan partials
#define SRCW_OFF  (1u << 20) // 800000 uint4 {src,tgt,w,0} = 12.8 MB
#define M_OFF     (1u << 24) // partial max rows: NE x 64 bf16 (sparse-touched ~10 MB)
#define WS_NEEDED ((size_t)(1u << 24) + (size_t)NE * 64u * 2u)
#define PB 196               // scan blocks: 196*256 >= NN

typedef __bf16 bf16x8 __attribute__((ext_vector_type(8)));
typedef float f32x16 __attribute__((ext_vector_type(16)));

union U4 { unsigned u[4]; __bf16 h[8]; bf16x8 v; };

__device__ __forceinline__ unsigned pkpair(float a, float b) {
  union { unsigned u; __bf16 h[2]; } r;
  r.h[0] = (__bf16)a; r.h[1] = (__bf16)b;
  return r.u;
}
__device__ __forceinline__ float bflo(unsigned u) { return __uint_as_float(u << 16); }
__device__ __forceinline__ float bfhi(unsigned u) { return __uint_as_float(u & 0xFFFF0000u); }

// ---- pass 1: count edges per target ----
extern "C" __global__ void __launch_bounds__(256)
count_kernel(const int* __restrict__ ei, unsigned* __restrict__ cnt) {
  const int e = blockIdx.x * 256 + threadIdx.x;
  if (e < NE) {
    int t = ei[NE + e];
    t = min(max(t, 0), NN - 1);
    atomicAdd(cnt + t, 1u);
  }
}

// ---- pass 1b: hierarchical exclusive scan cnt -> base ----
extern "C" __global__ void __launch_bounds__(256)
scan_a_kernel(const unsigned* __restrict__ cnt, unsigned* __restrict__ partial) {
  __shared__ unsigned wsum[4];
  const int t = threadIdx.x, wv = t >> 6, ln = t & 63;
  const int i = blockIdx.x * 256 + t;
  unsigned v = (i < NN) ? cnt[i] : 0u;
  #pragma unroll
  for (int d = 1; d < 64; d <<= 1) v += (unsigned)__shfl_up((int)v, d) * (ln >= d ? 1u : 0u);
  if (ln == 63) wsum[wv] = v;
  __syncthreads();
  if (t == 0) partial[blockIdx.x] = wsum[0] + wsum[1] + wsum[2] + wsum[3];
}

extern "C" __global__ void __launch_bounds__(256)
scan_b_kernel(unsigned* __restrict__ partial, unsigned* __restrict__ base) {
  __shared__ unsigned wsum[4];
  const int t = threadIdx.x, wv = t >> 6, ln = t & 63;
  const unsigned v = (t < PB) ? partial[t] : 0u;
  unsigned s = v;
  #pragma unroll
  for (int d = 1; d < 64; d <<= 1) s += (unsigned)__shfl_up((int)s, d) * (ln >= d ? 1u : 0u);
  if (ln == 63) wsum[wv] = s;
  __syncthreads();
  unsigned woff = 0;
  #pragma unroll
  for (int k = 0; k < 4; ++k) woff += (k < wv) ? wsum[k] : 0u;
  if (t < PB) partial[t] = woff + s - v;  // exclusive
  if (t == 255) base[NN] = woff + s;      // total (== NE)
}

extern "C" __global__ void __launch_bounds__(256)
scan_c_kernel(const unsigned* __restrict__ cnt, const unsigned* __restrict__ partial,
              unsigned* __restrict__ base) {
  __shared__ unsigned wsum[4];
  const int t = threadIdx.x, wv = t >> 6, ln = t & 63;
  const int i = blockIdx.x * 256 + t;
  const unsigned v = (i < NN) ? cnt[i] : 0u;
  unsigned s = v;
  #pragma unroll
  for (int d = 1; d < 64; d <<= 1) s += (unsigned)__shfl_up((int)s, d) * (ln >= d ? 1u : 0u);
  if (ln == 63) wsum[wv] = s;
  __syncthreads();
  unsigned woff = 0;
  #pragma unroll
  for (int k = 0; k < 4; ++k) woff += (k < wv) ? wsum[k] : 0u;
  if (i < NN) base[i] = partial[blockIdx.x] + woff + s - v;
}

// ---- pass 1c: scatter packed edge records to CSR positions ----
extern "C" __global__ void __launch_bounds__(256)
fill_kernel(const int* __restrict__ ei, const float* __restrict__ ew,
            const unsigned* __restrict__ base, unsigned* __restrict__ cnt2,
            uint4* __restrict__ srcw) {
  const int e = blockIdx.x * 256 + threadIdx.x;
  if (e < NE) {
    int s = min(max(ei[e], 0), NN - 1);
    int t = min(max(ei[NE + e], 0), NN - 1);
    const unsigned pos = base[t] + atomicAdd(cnt2 + t, 1u);
    uint4 rec;
    rec.x = (unsigned)s; rec.y = (unsigned)t;
    rec.z = __float_as_uint(ew[e]); rec.w = 0u;
    srcw[pos] = rec;
  }
}

// ---- pass 2: per-edge MLP in CSR order; wave-segmented max; leader stores ----
extern "C" __global__ void __launch_bounds__(256)
edge_mlp_kernel(const float* __restrict__ x, const float* __restrict__ ew,
                const int* __restrict__ ei, const float* __restrict__ w1,
                const float* __restrict__ w2, const float* __restrict__ w3,
                const float* __restrict__ g1, const float* __restrict__ b1,
                const float* __restrict__ g2, const float* __restrict__ b2,
                const float* __restrict__ g3, const float* __restrict__ b3,
                const uint4* __restrict__ srcw /* CSR records; null => fallback */,
                unsigned* __restrict__ agg /* fallback */,
                unsigned short* __restrict__ pmax /* partial-max rows */) {
  __shared__ unsigned lds_w[8192];  // 32 frags x 64 lanes x 16B = 32 KB
  const int tid = threadIdx.x;

  // ---- stage w1 (16 frags): slot j <-> k = 16t + 8g + j ----
  #pragma unroll 1
  for (int s = tid; s < 1024; s += 256) {
    const int F = s >> 6, L = s & 63;
    const int t = F >> 1, mt = F & 1;
    const int gg = L >> 5, o = (L & 31) + 32 * mt;
    const float* p = w1 + o * 128 + 16 * t + 8 * gg;
    unsigned* d = &lds_w[(unsigned)(F * 64 + L) * 4u];
    d[0] = pkpair(p[0], p[1]); d[1] = pkpair(p[2], p[3]);
    d[2] = pkpair(p[4], p[5]); d[3] = pkpair(p[6], p[7]);
  }
  // ---- stage w2/w3 (8 frags each): slot j <-> k = 16t + 4g + (j&3) + 8*(j>>2) ----
  #pragma unroll 1
  for (int s = tid; s < 1024; s += 256) {
    const int which = s >> 9, r = s & 511;
    const int F = r >> 6, L = r & 63;
    const int t = F >> 1, mt = F & 1;
    const int gg = L >> 5, o = (L & 31) + 32 * mt;
    const float* W = which ? w3 : w2;
    const float* p = W + o * 64 + 16 * t + 4 * gg;
    unsigned* d = &lds_w[(unsigned)((16 + which * 8 + F) * 64 + L) * 4u];
    d[0] = pkpair(p[0], p[1]); d[1] = pkpair(p[2], p[3]);
    d[2] = pkpair(p[8], p[9]); d[3] = pkpair(p[10], p[11]);
  }
  __syncthreads();

  const int lane = tid & 63;
  const int el = lane & 31;
  const int g = lane >> 5;
  const bf16x8* wfrag = (const bf16x8*)lds_w;

  const int wid = blockIdx.x * 4 + (tid >> 6);
  const int nw = gridDim.x * 4;

  // ---- index prefetch (one tile ahead) ----
  int tile = wid;
  int pvs = 0, pvt = 0; float pw = 0.f;
  if (tile < NT) {
    const int p0 = tile * 32 + el;
    if (srcw) {
      const uint4 rec = srcw[p0];
      pvs = (int)rec.x; pvt = (int)rec.y; pw = __uint_as_float(rec.z);
    } else {
      pvs = min(max(ei[p0], 0), NN - 1);
      pvt = min(max(ei[NE + p0], 0), NN - 1);
      pw = ew[p0];
    }
  }

  while (tile < NT) {
    const float* g1p = g1; const float* b1p = b1;
    const float* g2p = g2; const float* b2p = b2;
    const float* g3p = g3; const float* b3p = b3;
    asm volatile("" : "+s"(g1p), "+s"(b1p), "+s"(g2p), "+s"(b2p), "+s"(g3p), "+s"(b3p));

    const int p = tile * 32 + el;
    const int vsrc = pvs, vtgt = pvt;
    const float wgt = pw;

    const float* xi = x + (size_t)vtgt * 64 + 8 * g;
    const float* xj = x + (size_t)vsrc * 64 + 8 * g;

    // ---- build m half-row, packed bf16; f32 stats on the fly ----
    unsigned mp[32];
    float sum = 0.f, ssq = 0.f;
    #pragma unroll
    for (int t = 0; t < 4; ++t) {
      float4 a = *(const float4*)(xi + 16 * t);
      float4 b = *(const float4*)(xi + 16 * t + 4);
      float4 c = *(const float4*)(xj + 16 * t);
      float4 d4 = *(const float4*)(xj + 16 * t + 4);
      float lo[8] = {a.x, a.y, a.z, a.w, b.x, b.y, b.z, b.w};
      float up[8] = {wgt * (c.x - a.x), wgt * (c.y - a.y), wgt * (c.z - a.z), wgt * (c.w - a.w),
                     wgt * (d4.x - b.x), wgt * (d4.y - b.y), wgt * (d4.z - b.z), wgt * (d4.w - b.w)};
      #pragma unroll
      for (int pp = 0; pp < 4; ++pp) {
        mp[4 * t + pp] = pkpair(lo[2 * pp], lo[2 * pp + 1]);
        mp[16 + 4 * t + pp] = pkpair(up[2 * pp], up[2 * pp + 1]);
      }
      #pragma unroll
      for (int j = 0; j < 8; ++j) {
        sum += lo[j] + up[j];
        ssq += lo[j] * lo[j] + up[j] * up[j];
      }
    }

    // ---- prefetch records for next tile (overlaps LN/MFMA below) ----
    const int ntile = tile + nw;
    if (ntile < NT) {
      const int pn = ntile * 32 + el;
      if (srcw) {
        const uint4 rec = srcw[pn];
        pvs = (int)rec.x; pvt = (int)rec.y; pw = __uint_as_float(rec.z);
      } else {
        pvs = min(max(ei[pn], 0), NN - 1);
        pvt = min(max(ei[NE + pn], 0), NN - 1);
        pw = ew[pn];
      }
    }

    sum += __shfl_xor(sum, 32);
    ssq += __shfl_xor(ssq, 32);
    const float mean1 = sum * (1.f / 128.f);
    const float rstd1 = rsqrtf(ssq * (1.f / 128.f) - mean1 * mean1 + 1e-5f);
    const float c01 = -mean1 * rstd1;

    // ---- LN1 affine + LeakyReLU -> B1 frags ----
    U4 B1[8];
    #pragma unroll
    for (int t = 0; t < 8; ++t) {
      const int kb = ((t < 4) ? 16 * t : 64 + 16 * (t - 4)) + 8 * g;
      float4 ga = *(const float4*)(g1p + kb);
      float4 gb = *(const float4*)(g1p + kb + 4);
      float4 ba = *(const float4*)(b1p + kb);
      float4 bb = *(const float4*)(b1p + kb + 4);
      float gv[8] = {ga.x, ga.y, ga.z, ga.w, gb.x, gb.y, gb.z, gb.w};
      float bv[8] = {ba.x, ba.y, ba.z, ba.w, bb.x, bb.y, bb.z, bb.w};
      #pragma unroll
      for (int pp = 0; pp < 4; ++pp) {
        const unsigned u = mp[4 * t + pp];
        float v0 = fmaf(bflo(u), rstd1, c01);
        float v1 = fmaf(bfhi(u), rstd1, c01);
        v0 = fmaf(v0, gv[2 * pp], bv[2 * pp]);
        v1 = fmaf(v1, gv[2 * pp + 1], bv[2 * pp + 1]);
        v0 = v0 > 0.f ? v0 : 0.2f * v0;
        v1 = v1 > 0.f ? v1 : 0.2f * v1;
        B1[t].h[2 * pp] = (__bf16)v0;
        B1[t].h[2 * pp + 1] = (__bf16)v1;
      }
    }

    // ---- stage 1 ----
    f32x16 C0, C1;
    #pragma unroll
    for (int i = 0; i < 16; ++i) { C0[i] = 0.f; C1[i] = 0.f; }
    #pragma unroll
    for (int t = 0; t < 8; ++t) {
      C0 = __builtin_amdgcn_mfma_f32_32x32x16_bf16(wfrag[(2 * t + 0) * 64 + lane], B1[t].v, C0, 0, 0, 0);
      C1 = __builtin_amdgcn_mfma_f32_32x32x16_bf16(wfrag[(2 * t + 1) * 64 + lane], B1[t].v, C1, 0, 0, 0);
    }

    // ---- LN2 -> B2 ----
    float s2 = 0.f, q2 = 0.f;
    #pragma unroll
    for (int i = 0; i < 16; ++i) {
      s2 += C0[i] + C1[i];
      q2 += C0[i] * C0[i] + C1[i] * C1[i];
    }
    s2 += __shfl_xor(s2, 32); q2 += __shfl_xor(q2, 32);
    const float mean2 = s2 * (1.f / 64.f);
    const float rstd2 = rsqrtf(q2 * (1.f / 64.f) - mean2 * mean2 + 1e-5f);
    const float c02 = -mean2 * rstd2;

    U4 B2[4];
    #pragma unroll
    for (int t2 = 0; t2 < 4; ++t2) {
      const int kb = 16 * t2 + 4 * g;
      float4 gA = *(const float4*)(g2p + kb);
      float4 gB = *(const float4*)(g2p + kb + 8);
      float4 bA = *(const float4*)(b2p + kb);
      float4 bB = *(const float4*)(b2p + kb + 8);
      float gv[8] = {gA.x, gA.y, gA.z, gA.w, gB.x, gB.y, gB.z, gB.w};
      float bv[8] = {bA.x, bA.y, bA.z, bA.w, bB.x, bB.y, bB.z, bB.w};
      #pragma unroll
      for (int j = 0; j < 8; ++j) {
        const int reg = 4 * (2 * (t2 & 1) + (j >> 2)) + (j & 3);
        float v = (t2 >> 1) ? C1[reg] : C0[reg];
        v = fmaf(v, rstd2, c02);
        v = fmaf(v, gv[j], bv[j]);
        v = v > 0.f ? v : 0.2f * v;
        B2[t2].h[j] = (__bf16)v;
      }
    }

    // ---- stage 2 ----
    f32x16 D0, D1;
    #pragma unroll
    for (int i = 0; i < 16; ++i) { D0[i] = 0.f; D1[i] = 0.f; }
    #pragma unroll
    for (int t2 = 0; t2 < 4; ++t2) {
      D0 = __builtin_amdgcn_mfma_f32_32x32x16_bf16(wfrag[(16 + 2 * t2 + 0) * 64 + lane], B2[t2].v, D0, 0, 0, 0);
      D1 = __builtin_amdgcn_mfma_f32_32x32x16_bf16(wfrag[(16 + 2 * t2 + 1) * 64 + lane], B2[t2].v, D1, 0, 0, 0);
    }

    // ---- LN3 -> B3 ----
    float s3 = 0.f, q3 = 0.f;
    #pragma unroll
    for (int i = 0; i < 16; ++i) {
      s3 += D0[i] + D1[i];
      q3 += D0[i] * D0[i] + D1[i] * D1[i];
    }
    s3 += __shfl_xor(s3, 32); q3 += __shfl_xor(q3, 32);
    const float mean3 = s3 * (1.f / 64.f);
    const float rstd3 = rsqrtf(q3 * (1.f / 64.f) - mean3 * mean3 + 1e-5f);
    const float c03 = -mean3 * rstd3;

    U4 B3[4];
    #pragma unroll
    for (int t2 = 0; t2 < 4; ++t2) {
      const int kb = 16 * t2 + 4 * g;
      float4 gA = *(const float4*)(g3p + kb);
      float4 gB = *(const float4*)(g3p + kb + 8);
      float4 bA = *(const float4*)(b3p + kb);
      float4 bB = *(const float4*)(b3p + kb + 8);
      float gv[8] = {gA.x, gA.y, gA.z, gA.w, gB.x, gB.y, gB.z, gB.w};
      float bv[8] = {bA.x, bA.y, bA.z, bA.w, bB.x, bB.y, bB.z, bB.w};
      #pragma unroll
      for (int j = 0; j < 8; ++j) {
        const int reg = 4 * (2 * (t2 & 1) + (j >> 2)) + (j & 3);
        float v = (t2 >> 1) ? D1[reg] : D0[reg];
        v = fmaf(v, rstd3, c03);
        v = fmaf(v, gv[j], bv[j]);
        v = v > 0.f ? v : 0.2f * v;
        B3[t2].h[j] = (__bf16)v;
      }
    }

    // ---- stage 3 ----
    f32x16 F0, F1;
    #pragma unroll
    for (int i = 0; i < 16; ++i) { F0[i] = 0.f; F1[i] = 0.f; }
    #pragma unroll
    for (int t2 = 0; t2 < 4; ++t2) {
      F0 = __builtin_amdgcn_mfma_f32_32x32x16_bf16(wfrag[(24 + 2 * t2 + 0) * 64 + lane], B3[t2].v, F0, 0, 0, 0);
      F1 = __builtin_amdgcn_mfma_f32_32x32x16_bf16(wfrag[(24 + 2 * t2 + 1) * 64 + lane], B3[t2].v, F1, 0, 0, 0);
    }

    if (srcw) {
      // ---- pack results to bf16 pairs (already-final values) ----
      unsigned P[16];
      #pragma unroll
      for (int q = 0; q < 4; ++q) {
        P[2 * q + 0] = pkpair(F0[4 * q + 0], F0[4 * q + 1]);
        P[2 * q + 1] = pkpair(F0[4 * q + 2], F0[4 * q + 3]);
        P[8 + 2 * q + 0] = pkpair(F1[4 * q + 0], F1[4 * q + 1]);
        P[8 + 2 * q + 1] = pkpair(F1[4 * q + 2], F1[4 * q + 3]);
      }
      // ---- segmented suffix-max across el (positions sorted by vtgt) ----
      #pragma unroll
      for (int d = 1; d < 32; d <<= 1) {
        const int ot = __shfl_down(vtgt, d, 32);
        const bool mrg = (ot == vtgt);
        #pragma unroll
        for (int i = 0; i < 16; ++i) {
          const unsigned pv = __shfl_down(P[i], d, 32);
          if (mrg) {
            const float a = fmaxf(bflo(P[i]), bflo(pv));
            const float b = fmaxf(bfhi(P[i]), bfhi(pv));
            P[i] = (__float_as_uint(a) >> 16) | (__float_as_uint(b) & 0xFFFF0000u);
          }
        }
      }
      // ---- run-leader stores one partial row at position p ----
      const int pt = __shfl_up(vtgt, 1, 32);
      if (el == 0 || pt != vtgt) {
        unsigned short* row = pmax + (size_t)p * 64;
        #pragma unroll
        for (int q = 0; q < 4; ++q) {
          uint2 lo; lo.x = P[2 * q]; lo.y = P[2 * q + 1];
          uint2 hi; hi.x = P[8 + 2 * q]; hi.y = P[8 + 2 * q + 1];
          *(uint2*)(row + 8 * q + 4 * g) = lo;
          *(uint2*)(row + 32 + 8 * q + 4 * g) = hi;
        }
      }
    } else {
      // ---- fallback epilogue: atomic max scatter ----
      unsigned* ap = agg + (size_t)vtgt * 64;
      #pragma unroll
      for (int mt = 0; mt < 2; ++mt) {
        #pragma unroll
        for (int reg = 0; reg < 16; ++reg) {
          const int f = (reg & 3) + 8 * (reg >> 2) + 4 * g + 32 * mt;
          float v = mt ? F1[reg] : F0[reg];
          unsigned u = __float_as_uint(v);
          unsigned key = (u & 0x80000000u) ? ~u : (u | 0x80000000u);
          atomicMax(ap + f, key);
        }
      }
    }

    tile = ntile;
  }
}

// ---- pass 3: per-node partial-row max + residual ----
extern "C" __global__ void __launch_bounds__(256)
gather_max_kernel(const float* __restrict__ x, const unsigned short* __restrict__ pmax,
                  const unsigned* __restrict__ base, float* __restrict__ out) {
  const int node = blockIdx.x * 4 + (threadIdx.x >> 6);
  const int lane = threadIdx.x & 63;
  if (node >= NN) return;

  const unsigned b0 = base[node];
  const unsigned b1 = base[node + 1];
  float maxv = -INFINITY;
  if (b1 > b0) {
    // partial rows live at position b0 and at each 32-boundary inside (b0, b1)
    maxv = __uint_as_float((unsigned)pmax[(size_t)b0 * 64 + lane] << 16);
    const unsigned k1 = (b1 - 1) >> 5;
    for (unsigned k = (b0 >> 5) + 1; k <= k1; ++k) {
      const float v = __uint_as_float((unsigned)pmax[((size_t)k << 5) * 64 + lane] << 16);
      maxv = fmaxf(maxv, v);
    }
  }
  const size_t o = (size_t)node * 64 + lane;
  out[o] = (maxv >= -3.0e38f ? maxv : 0.f) + x[o];
}

// ---- fallback finalize (atomic path) ----
extern "C" __global__ void __launch_bounds__(256)
finalize_kernel(const float* __restrict__ x, unsigned* __restrict__ out) {
  const int i = blockIdx.x * 256 + threadIdx.x;
  if (i < NN * 64) {
    const unsigned key = out[i];
    const unsigned u = (key & 0x80000000u) ? (key & 0x7FFFFFFFu) : ~key;
    float v = __uint_as_float(u);
    if (((u >> 23) & 0xFFu) == 0xFFu) v = 0.f;
    ((float*)out)[i] = v + x[i];
  }
}

extern "C" void kernel_launch(void* const* d_in, const int* in_sizes, int n_in,
                              void* d_out, int out_size, void* d_ws, size_t ws_size,
                              hipStream_t stream) {
  (void)in_sizes; (void)n_in; (void)out_size;
  const float* x  = (const float*)d_in[0];
  const float* ew = (const float*)d_in[1];
  const int*   ei = (const int*)d_in[2];
  const float* w1 = (const float*)d_in[3];
  const float* w2 = (const float*)d_in[4];
  const float* w3 = (const float*)d_in[5];
  const float* g1 = (const float*)d_in[6];
  const float* b1 = (const float*)d_in[7];
  const float* g2 = (const float*)d_in[8];
  const float* b2 = (const float*)d_in[9];
  const float* g3 = (const float*)d_in[10];
  const float* b3 = (const float*)d_in[11];

  if (ws_size >= WS_NEEDED) {
    unsigned* cnt  = (unsigned*)((char*)d_ws + CNT_OFF);
    unsigned* cnt2 = (unsigned*)((char*)d_ws + CNT2_OFF);
    unsigned* base = (unsigned*)((char*)d_ws + BASE_OFF);
    unsigned* part = (unsigned*)((char*)d_ws + PART_OFF);
    uint4*    srcw = (uint4*)((char*)d_ws + SRCW_OFF);
    unsigned short* pmax = (unsigned short*)((char*)d_ws + M_OFF);

    hipMemsetAsync(d_ws, 0, BASE_OFF, stream);  // zero cnt + cnt2
    count_kernel<<<(NE + 255) / 256, 256, 0, stream>>>(ei, cnt);
    scan_a_kernel<<<PB, 256, 0, stream>>>(cnt, part);
    scan_b_kernel<<<1, 256, 0, stream>>>(part, base);
    scan_c_kernel<<<PB, 256, 0, stream>>>(cnt, part, base);
    fill_kernel<<<(NE + 255) / 256, 256, 0, stream>>>(ei, ew, base, cnt2, srcw);
    edge_mlp_kernel<<<2048, 256, 0, stream>>>(x, ew, ei, w1, w2, w3,
                                              g1, b1, g2, b2, g3, b3,
                                              srcw, nullptr, pmax);
    gather_max_kernel<<<(NN + 3) / 4, 256, 0, stream>>>(x, pmax, base, (float*)d_out);
  } else {
    unsigned* agg = (unsigned*)d_out;
    hipMemsetAsync(d_out, 0, (size_t)NN * 64 * sizeof(float), stream);
    edge_mlp_kernel<<<1024, 256, 0, stream>>>(x, ew, ei, w1, w2, w3,
                                              g1, b1, g2, b2, g3, b3,
                                              nullptr, agg, nullptr);
    finalize_kernel<<<(NN * 64 + 255) / 256, 256, 0, stream>>>(x, (unsigned*)d_out);
  }
}

// Round 7
// 278.336 us; speedup vs baseline: 1.2579x; 1.2579x over previous
//
#include <hip/hip_runtime.h>

#define NN 50000
#define NE 800000
#define NT (NE / 32)

// workspace layout (CSR + wave-reduced partials) — same WS_NEEDED as R6
#define CNT_OFF   0u         // 50000 u32 (200 KB)
#define BASE_OFF  204800u    // 50001 u32
#define PART_OFF  409600u    // 196 u32 scan partials
#define SLOT_OFF  417792u    // 800000 u32 per-edge slot (3.2 MB)
#define SRCW_OFF  3670016u   // 800000 uint4 {src,tgt,w,0} = 12.8 MB, ends < 1<<24
#define M_OFF     (1u << 24) // partial max rows: NE x 64 bf16 (sparse-touched)
#define WS_NEEDED ((size_t)(1u << 24) + (size_t)NE * 64u * 2u)
#define PB 196               // scan blocks: 196*256 >= NN

typedef __bf16 bf16x8 __attribute__((ext_vector_type(8)));
typedef float f32x16 __attribute__((ext_vector_type(16)));

union U4 { unsigned u[4]; __bf16 h[8]; bf16x8 v; };

__device__ __forceinline__ unsigned pkpair(float a, float b) {
  union { unsigned u; __bf16 h[2]; } r;
  r.h[0] = (__bf16)a; r.h[1] = (__bf16)b;
  return r.u;
}
__device__ __forceinline__ float bflo(unsigned u) { return __uint_as_float(u << 16); }
__device__ __forceinline__ float bfhi(unsigned u) { return __uint_as_float(u & 0xFFFF0000u); }

// ---- pass 1: count + slot assignment ----
extern "C" __global__ void __launch_bounds__(256)
scatter_kernel(const int* __restrict__ ei, unsigned* __restrict__ cnt,
               unsigned* __restrict__ slot) {
  const int e = blockIdx.x * 256 + threadIdx.x;
  if (e < NE) {
    int t = ei[NE + e];
    t = min(max(t, 0), NN - 1);
    slot[e] = atomicAdd(cnt + t, 1u);
  }
}

// ---- pass 1b: hierarchical exclusive scan cnt -> base ----
extern "C" __global__ void __launch_bounds__(256)
scan_a_kernel(const unsigned* __restrict__ cnt, unsigned* __restrict__ partial) {
  __shared__ unsigned wsum[4];
  const int t = threadIdx.x, wv = t >> 6, ln = t & 63;
  const int i = blockIdx.x * 256 + t;
  unsigned v = (i < NN) ? cnt[i] : 0u;
  #pragma unroll
  for (int d = 1; d < 64; d <<= 1) v += (unsigned)__shfl_up((int)v, d) * (ln >= d ? 1u : 0u);
  if (ln == 63) wsum[wv] = v;
  __syncthreads();
  if (t == 0) partial[blockIdx.x] = wsum[0] + wsum[1] + wsum[2] + wsum[3];
}

extern "C" __global__ void __launch_bounds__(256)
scan_b_kernel(unsigned* __restrict__ partial, unsigned* __restrict__ base) {
  __shared__ unsigned wsum[4];
  const int t = threadIdx.x, wv = t >> 6, ln = t & 63;
  const unsigned v = (t < PB) ? partial[t] : 0u;
  unsigned s = v;
  #pragma unroll
  for (int d = 1; d < 64; d <<= 1) s += (unsigned)__shfl_up((int)s, d) * (ln >= d ? 1u : 0u);
  if (ln == 63) wsum[wv] = s;
  __syncthreads();
  unsigned woff = 0;
  #pragma unroll
  for (int k = 0; k < 4; ++k) woff += (k < wv) ? wsum[k] : 0u;
  if (t < PB) partial[t] = woff + s - v;  // exclusive
  if (t == 255) base[NN] = woff + s;      // total (== NE)
}

extern "C" __global__ void __launch_bounds__(256)
scan_c_kernel(const unsigned* __restrict__ cnt, const unsigned* __restrict__ partial,
              unsigned* __restrict__ base) {
  __shared__ unsigned wsum[4];
  const int t = threadIdx.x, wv = t >> 6, ln = t & 63;
  const int i = blockIdx.x * 256 + t;
  const unsigned v = (i < NN) ? cnt[i] : 0u;
  unsigned s = v;
  #pragma unroll
  for (int d = 1; d < 64; d <<= 1) s += (unsigned)__shfl_up((int)s, d) * (ln >= d ? 1u : 0u);
  if (ln == 63) wsum[wv] = s;
  __syncthreads();
  unsigned woff = 0;
  #pragma unroll
  for (int k = 0; k < 4; ++k) woff += (k < wv) ? wsum[k] : 0u;
  if (i < NN) base[i] = partial[blockIdx.x] + woff + s - v;
}

// ---- pass 1c: reorder packed edge records to CSR positions (no atomics) ----
extern "C" __global__ void __launch_bounds__(256)
reorder_kernel(const int* __restrict__ ei, const float* __restrict__ ew,
               const unsigned* __restrict__ base, const unsigned* __restrict__ slot,
               uint4* __restrict__ srcw) {
  const int e = blockIdx.x * 256 + threadIdx.x;
  if (e < NE) {
    const int s = min(max(ei[e], 0), NN - 1);
    const int t = min(max(ei[NE + e], 0), NN - 1);
    const unsigned pos = base[t] + slot[e];
    uint4 rec;
    rec.x = (unsigned)s; rec.y = (unsigned)t;
    rec.z = __float_as_uint(ew[e]); rec.w = 0u;
    srcw[pos] = rec;
  }
}

// ---- pass 2: per-edge MLP in CSR order; wave-segmented max; leader stores ----
extern "C" __global__ void __launch_bounds__(256, 3)
edge_mlp_kernel(const float* __restrict__ x, const float* __restrict__ w1,
                const float* __restrict__ w2, const float* __restrict__ w3,
                const float* __restrict__ g1, const float* __restrict__ b1,
                const float* __restrict__ g2, const float* __restrict__ b2,
                const float* __restrict__ g3, const float* __restrict__ b3,
                const uint4* __restrict__ srcw,
                unsigned short* __restrict__ pmax) {
  __shared__ unsigned lds_w[8192];  // 32 frags x 64 lanes x 16B = 32 KB
  __shared__ float lds_p[512];      // params: g1|b1 (128 ea), g2|b2|g3|b3 (64 ea)
  const int tid = threadIdx.x;

  // ---- stage w1 (16 frags): slot j <-> k = 16t + 8g + j ----
  #pragma unroll 1
  for (int s = tid; s < 1024; s += 256) {
    const int F = s >> 6, L = s & 63;
    const int t = F >> 1, mt = F & 1;
    const int gg = L >> 5, o = (L & 31) + 32 * mt;
    const float* p = w1 + o * 128 + 16 * t + 8 * gg;
    unsigned* d = &lds_w[(unsigned)(F * 64 + L) * 4u];
    d[0] = pkpair(p[0], p[1]); d[1] = pkpair(p[2], p[3]);
    d[2] = pkpair(p[4], p[5]); d[3] = pkpair(p[6], p[7]);
  }
  // ---- stage w2/w3 (8 frags each): slot j <-> k = 16t + 4g + (j&3) + 8*(j>>2) ----
  #pragma unroll 1
  for (int s = tid; s < 1024; s += 256) {
    const int which = s >> 9, r = s & 511;
    const int F = r >> 6, L = r & 63;
    const int t = F >> 1, mt = F & 1;
    const int gg = L >> 5, o = (L & 31) + 32 * mt;
    const float* W = which ? w3 : w2;
    const float* p = W + o * 64 + 16 * t + 4 * gg;
    unsigned* d = &lds_w[(unsigned)((16 + which * 8 + F) * 64 + L) * 4u];
    d[0] = pkpair(p[0], p[1]); d[1] = pkpair(p[2], p[3]);
    d[2] = pkpair(p[8], p[9]); d[3] = pkpair(p[10], p[11]);
  }
  // ---- stage LN params into LDS ----
  #pragma unroll 1
  for (int s = tid; s < 512; s += 256) {
    float v;
    if (s < 128)      v = g1[s];
    else if (s < 256) v = b1[s - 128];
    else if (s < 320) v = g2[s - 256];
    else if (s < 384) v = b2[s - 320];
    else if (s < 448) v = g3[s - 384];
    else              v = b3[s - 448];
    lds_p[s] = v;
  }
  __syncthreads();

  const int lane = tid & 63;
  const int el = lane & 31;
  const int g = lane >> 5;
  const bf16x8* wfrag = (const bf16x8*)lds_w;

  const int wid = blockIdx.x * 4 + (tid >> 6);
  const int nw = gridDim.x * 4;

  // ---- record prefetch (one tile ahead) ----
  int tile = wid;
  int pvs = 0, pvt = 0; float pw = 0.f;
  if (tile < NT) {
    const uint4 rec = srcw[tile * 32 + el];
    pvs = (int)rec.x; pvt = (int)rec.y; pw = __uint_as_float(rec.z);
  }

  while (tile < NT) {
    // prevent LICM of per-tile LDS/param reads into ~100 long-lived VGPRs
    asm volatile("" ::: "memory");

    const int p = tile * 32 + el;
    const int vsrc = pvs, vtgt = pvt;
    const float wgt = pw;

    const float* xi = x + (size_t)vtgt * 64 + 8 * g;
    const float* xj = x + (size_t)vsrc * 64 + 8 * g;

    // ---- build m half-row, packed bf16; f32 stats on the fly ----
    unsigned mp[32];
    float sum = 0.f, ssq = 0.f;
    #pragma unroll
    for (int t = 0; t < 4; ++t) {
      float4 a = *(const float4*)(xi + 16 * t);
      float4 b = *(const float4*)(xi + 16 * t + 4);
      float4 c = *(const float4*)(xj + 16 * t);
      float4 d4 = *(const float4*)(xj + 16 * t + 4);
      float lo[8] = {a.x, a.y, a.z, a.w, b.x, b.y, b.z, b.w};
      float up[8] = {wgt * (c.x - a.x), wgt * (c.y - a.y), wgt * (c.z - a.z), wgt * (c.w - a.w),
                     wgt * (d4.x - b.x), wgt * (d4.y - b.y), wgt * (d4.z - b.z), wgt * (d4.w - b.w)};
      #pragma unroll
      for (int pp = 0; pp < 4; ++pp) {
        mp[4 * t + pp] = pkpair(lo[2 * pp], lo[2 * pp + 1]);
        mp[16 + 4 * t + pp] = pkpair(up[2 * pp], up[2 * pp + 1]);
      }
      #pragma unroll
      for (int j = 0; j < 8; ++j) {
        sum += lo[j] + up[j];
        ssq += lo[j] * lo[j] + up[j] * up[j];
      }
    }

    // ---- prefetch records for next tile (overlaps LN/MFMA below) ----
    const int ntile = tile + nw;
    if (ntile < NT) {
      const uint4 rec = srcw[ntile * 32 + el];
      pvs = (int)rec.x; pvt = (int)rec.y; pw = __uint_as_float(rec.z);
    }

    sum += __shfl_xor(sum, 32);
    ssq += __shfl_xor(ssq, 32);
    const float mean1 = sum * (1.f / 128.f);
    const float rstd1 = rsqrtf(ssq * (1.f / 128.f) - mean1 * mean1 + 1e-5f);
    const float c01 = -mean1 * rstd1;

    // ---- LN1 affine + LeakyReLU -> B1 frags ----
    U4 B1[8];
    #pragma unroll
    for (int t = 0; t < 8; ++t) {
      const int kb = ((t < 4) ? 16 * t : 64 + 16 * (t - 4)) + 8 * g;
      float4 ga = *(const float4*)(lds_p + kb);
      float4 gb = *(const float4*)(lds_p + kb + 4);
      float4 ba = *(const float4*)(lds_p + 128 + kb);
      float4 bb = *(const float4*)(lds_p + 128 + kb + 4);
      float gv[8] = {ga.x, ga.y, ga.z, ga.w, gb.x, gb.y, gb.z, gb.w};
      float bv[8] = {ba.x, ba.y, ba.z, ba.w, bb.x, bb.y, bb.z, bb.w};
      #pragma unroll
      for (int pp = 0; pp < 4; ++pp) {
        const unsigned u = mp[4 * t + pp];
        float v0 = fmaf(bflo(u), rstd1, c01);
        float v1 = fmaf(bfhi(u), rstd1, c01);
        v0 = fmaf(v0, gv[2 * pp], bv[2 * pp]);
        v1 = fmaf(v1, gv[2 * pp + 1], bv[2 * pp + 1]);
        v0 = fmaxf(v0, 0.2f * v0);
        v1 = fmaxf(v1, 0.2f * v1);
        B1[t].h[2 * pp] = (__bf16)v0;
        B1[t].h[2 * pp + 1] = (__bf16)v1;
      }
    }

    // ---- stage 1 (accumulators A0/A1, reused by all 3 stages) ----
    f32x16 A0, A1;
    #pragma unroll
    for (int i = 0; i < 16; ++i) { A0[i] = 0.f; A1[i] = 0.f; }
    #pragma unroll
    for (int t = 0; t < 8; ++t) {
      A0 = __builtin_amdgcn_mfma_f32_32x32x16_bf16(wfrag[(2 * t + 0) * 64 + lane], B1[t].v, A0, 0, 0, 0);
      A1 = __builtin_amdgcn_mfma_f32_32x32x16_bf16(wfrag[(2 * t + 1) * 64 + lane], B1[t].v, A1, 0, 0, 0);
    }

    // ---- LN2 -> B2 ----
    float s2 = 0.f, q2 = 0.f;
    #pragma unroll
    for (int i = 0; i < 16; ++i) {
      s2 += A0[i] + A1[i];
      q2 += A0[i] * A0[i] + A1[i] * A1[i];
    }
    s2 += __shfl_xor(s2, 32); q2 += __shfl_xor(q2, 32);
    const float mean2 = s2 * (1.f / 64.f);
    const float rstd2 = rsqrtf(q2 * (1.f / 64.f) - mean2 * mean2 + 1e-5f);
    const float c02 = -mean2 * rstd2;

    U4 B2[4];
    #pragma unroll
    for (int t2 = 0; t2 < 4; ++t2) {
      const int kb = 16 * t2 + 4 * g;
      float4 gA = *(const float4*)(lds_p + 256 + kb);
      float4 gB = *(const float4*)(lds_p + 256 + kb + 8);
      float4 bA = *(const float4*)(lds_p + 320 + kb);
      float4 bB = *(const float4*)(lds_p + 320 + kb + 8);
      float gv[8] = {gA.x, gA.y, gA.z, gA.w, gB.x, gB.y, gB.z, gB.w};
      float bv[8] = {bA.x, bA.y, bA.z, bA.w, bB.x, bB.y, bB.z, bB.w};
      #pragma unroll
      for (int j = 0; j < 8; ++j) {
        const int reg = 4 * (2 * (t2 & 1) + (j >> 2)) + (j & 3);
        float v = (t2 >> 1) ? A1[reg] : A0[reg];
        v = fmaf(v, rstd2, c02);
        v = fmaf(v, gv[j], bv[j]);
        v = fmaxf(v, 0.2f * v);
        B2[t2].h[j] = (__bf16)v;
      }
    }

    // ---- stage 2 (reuse A0/A1) ----
    #pragma unroll
    for (int i = 0; i < 16; ++i) { A0[i] = 0.f; A1[i] = 0.f; }
    #pragma unroll
    for (int t2 = 0; t2 < 4; ++t2) {
      A0 = __builtin_amdgcn_mfma_f32_32x32x16_bf16(wfrag[(16 + 2 * t2 + 0) * 64 + lane], B2[t2].v, A0, 0, 0, 0);
      A1 = __builtin_amdgcn_mfma_f32_32x32x16_bf16(wfrag[(16 + 2 * t2 + 1) * 64 + lane], B2[t2].v, A1, 0, 0, 0);
    }

    // ---- LN3 -> B3 ----
    float s3 = 0.f, q3 = 0.f;
    #pragma unroll
    for (int i = 0; i < 16; ++i) {
      s3 += A0[i] + A1[i];
      q3 += A0[i] * A0[i] + A1[i] * A1[i];
    }
    s3 += __shfl_xor(s3, 32); q3 += __shfl_xor(q3, 32);
    const float mean3 = s3 * (1.f / 64.f);
    const float rstd3 = rsqrtf(q3 * (1.f / 64.f) - mean3 * mean3 + 1e-5f);
    const float c03 = -mean3 * rstd3;

    U4 B3[4];
    #pragma unroll
    for (int t2 = 0; t2 < 4; ++t2) {
      const int kb = 16 * t2 + 4 * g;
      float4 gA = *(const float4*)(lds_p + 384 + kb);
      float4 gB = *(const float4*)(lds_p + 384 + kb + 8);
      float4 bA = *(const float4*)(lds_p + 448 + kb);
      float4 bB = *(const float4*)(lds_p + 448 + kb + 8);
      float gv[8] = {gA.x, gA.y, gA.z, gA.w, gB.x, gB.y, gB.z, gB.w};
      float bv[8] = {bA.x, bA.y, bA.z, bA.w, bB.x, bB.y, bB.z, bB.w};
      #pragma unroll
      for (int j = 0; j < 8; ++j) {
        const int reg = 4 * (2 * (t2 & 1) + (j >> 2)) + (j & 3);
        float v = (t2 >> 1) ? A1[reg] : A0[reg];
        v = fmaf(v, rstd3, c03);
        v = fmaf(v, gv[j], bv[j]);
        v = fmaxf(v, 0.2f * v);
        B3[t2].h[j] = (__bf16)v;
      }
    }

    // ---- stage 3 (reuse A0/A1) ----
    #pragma unroll
    for (int i = 0; i < 16; ++i) { A0[i] = 0.f; A1[i] = 0.f; }
    #pragma unroll
    for (int t2 = 0; t2 < 4; ++t2) {
      A0 = __builtin_amdgcn_mfma_f32_32x32x16_bf16(wfrag[(24 + 2 * t2 + 0) * 64 + lane], B3[t2].v, A0, 0, 0, 0);
      A1 = __builtin_amdgcn_mfma_f32_32x32x16_bf16(wfrag[(24 + 2 * t2 + 1) * 64 + lane], B3[t2].v, A1, 0, 0, 0);
    }

    // ---- pack results to bf16 pairs ----
    unsigned P[16];
    #pragma unroll
    for (int q = 0; q < 4; ++q) {
      P[2 * q + 0] = pkpair(A0[4 * q + 0], A0[4 * q + 1]);
      P[2 * q + 1] = pkpair(A0[4 * q + 2], A0[4 * q + 3]);
      P[8 + 2 * q + 0] = pkpair(A1[4 * q + 0], A1[4 * q + 1]);
      P[8 + 2 * q + 1] = pkpair(A1[4 * q + 2], A1[4 * q + 3]);
    }
    // ---- segmented suffix-max across el (positions sorted by vtgt) ----
    #pragma unroll
    for (int d = 1; d < 32; d <<= 1) {
      const int ot = __shfl_down(vtgt, d, 32);
      const bool mrg = (ot == vtgt);
      #pragma unroll
      for (int i = 0; i < 16; ++i) {
        const unsigned pv = __shfl_down(P[i], d, 32);
        if (mrg) {
          const float a = fmaxf(bflo(P[i]), bflo(pv));
          const float b = fmaxf(bfhi(P[i]), bfhi(pv));
          P[i] = (__float_as_uint(a) >> 16) | (__float_as_uint(b) & 0xFFFF0000u);
        }
      }
    }
    // ---- run-leader stores one partial row at position p ----
    const int pt = __shfl_up(vtgt, 1, 32);
    if (el == 0 || pt != vtgt) {
      unsigned short* row = pmax + (size_t)p * 64;
      #pragma unroll
      for (int q = 0; q < 4; ++q) {
        uint2 lo; lo.x = P[2 * q]; lo.y = P[2 * q + 1];
        uint2 hi; hi.x = P[8 + 2 * q]; hi.y = P[8 + 2 * q + 1];
        *(uint2*)(row + 8 * q + 4 * g) = lo;
        *(uint2*)(row + 32 + 8 * q + 4 * g) = hi;
      }
    }

    tile = ntile;
  }
}

// ---- pass 3: per-node partial-row max + residual ----
extern "C" __global__ void __launch_bounds__(256)
gather_max_kernel(const float* __restrict__ x, const unsigned short* __restrict__ pmax,
                  const unsigned* __restrict__ base, float* __restrict__ out) {
  const int node = blockIdx.x * 4 + (threadIdx.x >> 6);
  const int lane = threadIdx.x & 63;
  if (node >= NN) return;

  const unsigned b0 = base[node];
  const unsigned b1 = base[node + 1];
  float maxv = -INFINITY;
  if (b1 > b0) {
    // partial rows live at position b0 and at each 32-boundary inside (b0, b1)
    maxv = __uint_as_float((unsigned)pmax[(size_t)b0 * 64 + lane] << 16);
    const unsigned k1 = (b1 - 1) >> 5;
    for (unsigned k = (b0 >> 5) + 1; k <= k1; ++k) {
      const float v = __uint_as_float((unsigned)pmax[((size_t)k << 5) * 64 + lane] << 16);
      maxv = fmaxf(maxv, v);
    }
  }
  const size_t o = (size_t)node * 64 + lane;
  out[o] = (maxv >= -3.0e38f ? maxv : 0.f) + x[o];
}

extern "C" void kernel_launch(void* const* d_in, const int* in_sizes, int n_in,
                              void* d_out, int out_size, void* d_ws, size_t ws_size,
                              hipStream_t stream) {
  (void)in_sizes; (void)n_in; (void)out_size; (void)ws_size;
  const float* x  = (const float*)d_in[0];
  const float* ew = (const float*)d_in[1];
  const int*   ei = (const int*)d_in[2];
  const float* w1 = (const float*)d_in[3];
  const float* w2 = (const float*)d_in[4];
  const float* w3 = (const float*)d_in[5];
  const float* g1 = (const float*)d_in[6];
  const float* b1 = (const float*)d_in[7];
  const float* g2 = (const float*)d_in[8];
  const float* b2 = (const float*)d_in[9];
  const float* g3 = (const float*)d_in[10];
  const float* b3 = (const float*)d_in[11];

  unsigned* cnt  = (unsigned*)((char*)d_ws + CNT_OFF);
  unsigned* base = (unsigned*)((char*)d_ws + BASE_OFF);
  unsigned* part = (unsigned*)((char*)d_ws + PART_OFF);
  unsigned* slot = (unsigned*)((char*)d_ws + SLOT_OFF);
  uint4*    srcw = (uint4*)((char*)d_ws + SRCW_OFF);
  unsigned short* pmax = (unsigned short*)((char*)d_ws + M_OFF);

  hipMemsetAsync(cnt, 0, (size_t)NN * sizeof(unsigned), stream);
  scatter_kernel<<<(NE + 255) / 256, 256, 0, stream>>>(ei, cnt, slot);
  scan_a_kernel<<<PB, 256, 0, stream>>>(cnt, part);
  scan_b_kernel<<<1, 256, 0, stream>>>(part, base);
  scan_c_kernel<<<PB, 256, 0, stream>>>(cnt, part, base);
  reorder_kernel<<<(NE + 255) / 256, 256, 0, stream>>>(ei, ew, base, slot, srcw);
  edge_mlp_kernel<<<2048, 256, 0, stream>>>(x, w1, w2, w3,
                                            g1, b1, g2, b2, g3, b3,
                                            srcw, pmax);
  gather_max_kernel<<<(NN + 3) / 4, 256, 0, stream>>>(x, pmax, base, (float*)d_out);
}